// Round 3
// baseline (154.262 us; speedup 1.0000x reference)
//
#include <hip/hip_runtime.h>

#define B_ 8
#define N_ 512
#define F_ 128
#define H_ 4
#define U_ 32
#define LEAKY_ALPHA 0.2f

// ---------------------------------------------------------------------------
// Kernel 1: projections.
//   hsrc[b,h,n,u]  =  sum_f x[b,n,f] * Wsrc[h,f,u]
//   hdstN[b,h,n,u] = -sum_f x[b,n,f] * Wdst[h,f,u]      (negated)
//   Drow[b,h,n]    =  sum_u a[h,u] * h_dst[b,h,n,u]     (true D)
//   ascaled[h,u]   =  0.8 * a[h,u]
// Score identity used downstream (0.2*A_i is row-constant -> dropped,
// softmax is shift-invariant):
//   score(i,j) ~ D_j + sum_u (0.8*a_u) * max(s_iu, -d_ju)
// ---------------------------------------------------------------------------
__global__ __launch_bounds__(256) void proj_kernel(
    const float* __restrict__ x, const float* __restrict__ Wsrc,
    const float* __restrict__ Wdst, const float* __restrict__ a,
    float* __restrict__ hsrc, float* __restrict__ hdstN,
    float* __restrict__ Drow, float* __restrict__ ascaled)
{
    __shared__ float4 xlds[8 * 32];           // 8 rows x 128 floats
    const int t  = threadIdx.x;
    const int r0 = blockIdx.x * 8;            // first flat row (b*N+n)

    const float4* xg = (const float4*)x + (size_t)r0 * 32;
    xlds[t] = xg[t];
    __syncthreads();

    const int u     = t & 31;
    const int h     = (t >> 5) & 3;
    const int which = t >> 7;                 // 0 = src, 1 = dst
    const float* W  = (which ? Wdst : Wsrc) + h * (F_ * U_) + u;

    float acc[8];
#pragma unroll
    for (int r = 0; r < 8; ++r) acc[r] = 0.f;

#pragma unroll 2
    for (int fc = 0; fc < 32; ++fc) {
        const float w0 = W[(4 * fc + 0) * U_];
        const float w1 = W[(4 * fc + 1) * U_];
        const float w2 = W[(4 * fc + 2) * U_];
        const float w3 = W[(4 * fc + 3) * U_];
#pragma unroll
        for (int r = 0; r < 8; ++r) {
            const float4 xv = xlds[r * 32 + fc];
            float s = acc[r];
            s = fmaf(xv.x, w0, s);
            s = fmaf(xv.y, w1, s);
            s = fmaf(xv.z, w2, s);
            s = fmaf(xv.w, w3, s);
            acc[r] = s;
        }
    }

    const float av = a[h * U_ + u];

    if (which == 1 && blockIdx.x == 0) ascaled[h * U_ + u] = (1.f - LEAKY_ALPHA) * av;

#pragma unroll
    for (int r = 0; r < 8; ++r) {
        const int row = r0 + r;               // = b*N + n
        const int b = row >> 9, n = row & (N_ - 1);
        const size_t base = ((size_t)((b * H_ + h) * N_ + n) << 5) + u;
        if (which == 0) {
            hsrc[base] = acc[r];
        } else {
            hdstN[base] = -acc[r];            // store negated d
            float v = acc[r] * av;            // reduce a_u*d over 32 u-lanes
            v += __shfl_xor(v, 1);
            v += __shfl_xor(v, 2);
            v += __shfl_xor(v, 4);
            v += __shfl_xor(v, 8);
            v += __shfl_xor(v, 16);
            if (u == 0) Drow[(b * H_ + h) * N_ + n] = v;
        }
    }
}

// ---------------------------------------------------------------------------
// Kernel 2: attention, lane-per-i layout.
// Block = 512 thr = 8 waves = one (bh, 64-i tile); wave w covers j in
// [64w, 64w+64). i = lane, so every d-row / src-row / Drow address in the
// main loop is WAVE-UNIFORM (readfirstlane on the wave id makes this
// provable) -> scalar or broadcast loads, near-zero memory-pipe cost.
// Per (i,j): 32 v_max + 32 v_fmac (score) + exp + 32 v_fmac (PV). No
// max-subtraction needed: |score| <~ 30 << 88 (exp overflow bound), and
// softmax is mathematically identical without the shift.
// Partial (o[32], l) per wave merged through LDS at the end.
// ---------------------------------------------------------------------------
__global__ __launch_bounds__(512) void attn_kernel(
    const float* __restrict__ hsrc, const float* __restrict__ hdstN,
    const float* __restrict__ Drow, const float* __restrict__ ascaled,
    float* __restrict__ out)
{
    __shared__ float oL[8 * 64 * 33];         // 67.6 KB partial o (stride 33)
    __shared__ float lL[8 * 64];              // partial l

    const int t    = threadIdx.x;
    const int lane = t & 63;
    const int wv   = __builtin_amdgcn_readfirstlane(t >> 6);
    const int tile = blockIdx.x & 7;          // 8 tiles of 64 i per bh
    const int bh   = blockIdx.x >> 3;
    const int h    = bh & 3;
    const int b    = bh >> 2;
    const size_t bhN = (size_t)bh * N_;
    const int ig   = tile * 64 + lane;

    // per-lane s-row into registers
    float s[32];
    {
        const float4* sg = (const float4*)(hsrc + ((bhN + ig) << 5));
#pragma unroll
        for (int q = 0; q < 8; ++q) {
            const float4 v = sg[q];
            s[4 * q + 0] = v.x; s[4 * q + 1] = v.y;
            s[4 * q + 2] = v.z; s[4 * q + 3] = v.w;
        }
    }
    const float* ap = ascaled + h * U_;       // uniform, 0.8*a

    float o[32];
#pragma unroll
    for (int u = 0; u < 32; ++u) o[u] = 0.f;
    float l = 0.f;

    const float* drows = hdstN + (bhN << 5);
    const float* srows = hsrc + (bhN << 5);
    const float* Dr    = Drow + bhN;
    const int jbase = wv * 64;

#pragma unroll 2
    for (int jc = 0; jc < 64; ++jc) {
        const int j = jbase + jc;
        const float* dr = drows + j * 32;     // uniform address
        const float* sr = srows + j * 32;     // uniform address
        float r0 = 0.f, r1 = 0.f, r2 = 0.f, r3 = 0.f;
#pragma unroll
        for (int u = 0; u < 32; u += 4) {
            r0 = fmaf(ap[u + 0], fmaxf(s[u + 0], dr[u + 0]), r0);
            r1 = fmaf(ap[u + 1], fmaxf(s[u + 1], dr[u + 1]), r1);
            r2 = fmaf(ap[u + 2], fmaxf(s[u + 2], dr[u + 2]), r2);
            r3 = fmaf(ap[u + 3], fmaxf(s[u + 3], dr[u + 3]), r3);
        }
        const float p = __expf(Dr[j] + ((r0 + r1) + (r2 + r3)));
        l += p;
#pragma unroll
        for (int u = 0; u < 32; ++u) o[u] = fmaf(p, sr[u], o[u]);
    }

    // write per-wave partials
    {
        float* ob = &oL[(wv * 64 + lane) * 33];
#pragma unroll
        for (int u = 0; u < 32; ++u) ob[u] = o[u];
        lL[wv * 64 + lane] = l;
    }
    __syncthreads();

    // combine: thread t -> (i = t&63, u-quad q = t>>6)
    {
        const int i = t & 63;
        const int q = t >> 6;
        float lsum = 0.f;
#pragma unroll
        for (int w = 0; w < 8; ++w) lsum += lL[w * 64 + i];
        const float inv = __builtin_amdgcn_rcpf(lsum);

        float a0 = 0.f, a1 = 0.f, a2 = 0.f, a3 = 0.f;
#pragma unroll
        for (int w = 0; w < 8; ++w) {
            const float* ob = &oL[(w * 64 + i) * 33 + 4 * q];
            a0 += ob[0]; a1 += ob[1]; a2 += ob[2]; a3 += ob[3];
        }
        const int igi = tile * 64 + i;
        float4 ov;
        ov.x = a0 * inv; ov.y = a1 * inv; ov.z = a2 * inv; ov.w = a3 * inv;
        *(float4*)&out[(size_t)(b * N_ + igi) * (H_ * U_) + h * U_ + 4 * q] = ov;
    }
}

// ---------------------------------------------------------------------------
extern "C" void kernel_launch(void* const* d_in, const int* in_sizes, int n_in,
                              void* d_out, int out_size, void* d_ws, size_t ws_size,
                              hipStream_t stream) {
    const float* x    = (const float*)d_in[0];
    const float* Wsrc = (const float*)d_in[1];
    const float* Wdst = (const float*)d_in[2];
    const float* a    = (const float*)d_in[3];

    float* ws      = (float*)d_ws;
    float* hsrc    = ws;
    float* hdstN   = hsrc + (size_t)B_ * H_ * N_ * U_;
    float* Drow    = hdstN + (size_t)B_ * H_ * N_ * U_;
    float* ascaled = Drow + (size_t)B_ * H_ * N_;

    proj_kernel<<<(B_ * N_) / 8, 256, 0, stream>>>(x, Wsrc, Wdst, a,
                                                   hsrc, hdstN, Drow, ascaled);
    attn_kernel<<<B_ * H_ * (N_ / 64), 512, 0, stream>>>(hsrc, hdstN, Drow,
                                                         ascaled, (float*)d_out);
}

// Round 4
// 119.983 us; speedup vs baseline: 1.2857x; 1.2857x over previous
//
#include <hip/hip_runtime.h>

#define B_ 8
#define N_ 512
#define F_ 128
#define H_ 4
#define U_ 32
#define LEAKY_ALPHA 0.2f

typedef __attribute__((ext_vector_type(8))) short short8;
typedef __attribute__((ext_vector_type(4))) float f32x4;

static __device__ __forceinline__ short f2bf(float x) {   // RNE float->bf16
    unsigned u = __float_as_uint(x);
    u = (u + 0x7FFFu + ((u >> 16) & 1u)) >> 16;
    return (short)u;
}
static __device__ __forceinline__ float bf2f(short b) {
    return __uint_as_float(((unsigned)(unsigned short)b) << 16);
}

// ---------------------------------------------------------------------------
// Kernel 1: projections (unchanged from R2/R3 — measured small).
//   hsrc = x@Wsrc ; hdstN = -(x@Wdst) ; Drow[j] = sum_u a_u d_ju ;
//   ascaled = 0.8*a.  score(i,j) ~ D_j + sum_u (0.8 a_u) max(s_iu, -d_ju)
//   (row-constant 0.2*A_i dropped; softmax shift-invariant).
// ---------------------------------------------------------------------------
__global__ __launch_bounds__(256) void proj_kernel(
    const float* __restrict__ x, const float* __restrict__ Wsrc,
    const float* __restrict__ Wdst, const float* __restrict__ a,
    float* __restrict__ hsrc, float* __restrict__ hdstN,
    float* __restrict__ Drow, float* __restrict__ ascaled)
{
    __shared__ float4 xlds[8 * 32];
    const int t  = threadIdx.x;
    const int r0 = blockIdx.x * 8;

    const float4* xg = (const float4*)x + (size_t)r0 * 32;
    xlds[t] = xg[t];
    __syncthreads();

    const int u     = t & 31;
    const int h     = (t >> 5) & 3;
    const int which = t >> 7;
    const float* W  = (which ? Wdst : Wsrc) + h * (F_ * U_) + u;

    float acc[8];
#pragma unroll
    for (int r = 0; r < 8; ++r) acc[r] = 0.f;

#pragma unroll 2
    for (int fc = 0; fc < 32; ++fc) {
        const float w0 = W[(4 * fc + 0) * U_];
        const float w1 = W[(4 * fc + 1) * U_];
        const float w2 = W[(4 * fc + 2) * U_];
        const float w3 = W[(4 * fc + 3) * U_];
#pragma unroll
        for (int r = 0; r < 8; ++r) {
            const float4 xv = xlds[r * 32 + fc];
            float s = acc[r];
            s = fmaf(xv.x, w0, s);
            s = fmaf(xv.y, w1, s);
            s = fmaf(xv.z, w2, s);
            s = fmaf(xv.w, w3, s);
            acc[r] = s;
        }
    }

    const float av = a[h * U_ + u];
    if (which == 1 && blockIdx.x == 0)
        ascaled[h * U_ + u] = (1.f - LEAKY_ALPHA) * av;

#pragma unroll
    for (int r = 0; r < 8; ++r) {
        const int row = r0 + r;
        const int b = row >> 9, n = row & (N_ - 1);
        const size_t base = ((size_t)((b * H_ + h) * N_ + n) << 5) + u;
        if (which == 0) {
            hsrc[base] = acc[r];
        } else {
            hdstN[base] = -acc[r];
            float v = acc[r] * av;
            v += __shfl_xor(v, 1);
            v += __shfl_xor(v, 2);
            v += __shfl_xor(v, 4);
            v += __shfl_xor(v, 8);
            v += __shfl_xor(v, 16);
            if (u == 0) Drow[(b * H_ + h) * N_ + n] = v;
        }
    }
}

// ---------------------------------------------------------------------------
// Kernel 2: attention. Block = 256 thr = 4 waves = 16 i (wave w owns i-quad
// 4w..4w+3); grid = 32 bh x 32 tiles = 1024 blocks.
// Phase A (VALU): half-wave u-split (s[4][16] regs), d-rows read straight
// from L2, score -> exp -> bf16 p into LDS (i-major, stride PS=520 bf16 to
// de-conflict b128 frag reads). l accumulated in fp32 from ROUNDED p.
// Phase C (MFMA): out_tile = p[16x512]@src[512x32] as 4 K-steps/wave of
// mfma_f32_16x16x32_bf16, two N-tiles; src pre-staged once as transposed
// bf16 (B-frag = 8 contiguous j at fixed u). Cross-wave K-reduction via an
// 8 KB scratch aliased onto the (dead) st buffer.
// ---------------------------------------------------------------------------
#define PS 520

__global__ __launch_bounds__(256, 3) void attn_kernel(
    const float* __restrict__ hsrc, const float* __restrict__ hdstN,
    const float* __restrict__ Drow, const float* __restrict__ ascaled,
    float* __restrict__ out)
{
    __shared__ __align__(16) short st[32 * PS];   // 33.3 KB src^T bf16 [u][j]
    __shared__ __align__(16) short pbf[16 * PS];  // 16.6 KB p bf16 [i][j]
    __shared__ float lfin[16];

    const int t  = threadIdx.x;
    const int L  = t & 63;
    const int w  = __builtin_amdgcn_readfirstlane(t >> 6);
    const int tile = blockIdx.x & 31;
    const int bh   = blockIdx.x >> 5;
    const int h    = bh & 3;
    const int b    = bh >> 2;
    const size_t bhN = (size_t)bh * N_;
    const int ig0  = tile * 16;

    // ---- stage st = bf16(hsrc[bh])^T, all 512 j (first read is post-barrier)
    {
        const float4* sg = (const float4*)(hsrc + (bhN << 5));
#pragma unroll
        for (int q = 0; q < 16; ++q) {
            const int idx = t + 256 * q;
            const int j = idx >> 3, ug = idx & 7;
            const float4 v = sg[idx];
            st[(4 * ug + 0) * PS + j] = f2bf(v.x);
            st[(4 * ug + 1) * PS + j] = f2bf(v.y);
            st[(4 * ug + 2) * PS + j] = f2bf(v.z);
            st[(4 * ug + 3) * PS + j] = f2bf(v.w);
        }
    }

    // ---- Phase A: scores -> p (bf16, LDS) + l (fp32 regs) ----
    const int uh  = (L >> 4) & 1;                 // u-half
    const int jlo = (L & 15) | ((L >> 5) << 4);   // 0..31

    float s[4][16];
#pragma unroll
    for (int ii = 0; ii < 4; ++ii) {
        const float4* sr = (const float4*)(hsrc + ((bhN + ig0 + 4 * w + ii) << 5) + uh * 16);
#pragma unroll
        for (int qq = 0; qq < 4; ++qq) {
            const float4 v = sr[qq];
            s[ii][4 * qq + 0] = v.x; s[ii][4 * qq + 1] = v.y;
            s[ii][4 * qq + 2] = v.z; s[ii][4 * qq + 3] = v.w;
        }
    }
    float ap[16];
    {
        const float4* ag = (const float4*)(ascaled + h * U_ + uh * 16);
#pragma unroll
        for (int qq = 0; qq < 4; ++qq) {
            const float4 v = ag[qq];
            ap[4 * qq + 0] = v.x; ap[4 * qq + 1] = v.y;
            ap[4 * qq + 2] = v.z; ap[4 * qq + 3] = v.w;
        }
    }

    float l0 = 0.f, l1 = 0.f, l2 = 0.f, l3 = 0.f;
    const float* dbase = hdstN + (bhN << 5);
    const float* Dr    = Drow + bhN;

#pragma unroll 2
    for (int k = 0; k < 16; ++k) {
        const int j = jlo + 32 * k;
        const float4* dr = (const float4*)(dbase + j * 32 + uh * 16);
        float r0 = 0.f, r1 = 0.f, r2 = 0.f, r3 = 0.f;
#pragma unroll
        for (int qq = 0; qq < 4; ++qq) {
            const float4 dv = dr[qq];
            r0 = fmaf(ap[4*qq+0], fmaxf(s[0][4*qq+0], dv.x), r0);
            r1 = fmaf(ap[4*qq+0], fmaxf(s[1][4*qq+0], dv.x), r1);
            r2 = fmaf(ap[4*qq+0], fmaxf(s[2][4*qq+0], dv.x), r2);
            r3 = fmaf(ap[4*qq+0], fmaxf(s[3][4*qq+0], dv.x), r3);
            r0 = fmaf(ap[4*qq+1], fmaxf(s[0][4*qq+1], dv.y), r0);
            r1 = fmaf(ap[4*qq+1], fmaxf(s[1][4*qq+1], dv.y), r1);
            r2 = fmaf(ap[4*qq+1], fmaxf(s[2][4*qq+1], dv.y), r2);
            r3 = fmaf(ap[4*qq+1], fmaxf(s[3][4*qq+1], dv.y), r3);
            r0 = fmaf(ap[4*qq+2], fmaxf(s[0][4*qq+2], dv.z), r0);
            r1 = fmaf(ap[4*qq+2], fmaxf(s[1][4*qq+2], dv.z), r1);
            r2 = fmaf(ap[4*qq+2], fmaxf(s[2][4*qq+2], dv.z), r2);
            r3 = fmaf(ap[4*qq+2], fmaxf(s[3][4*qq+2], dv.z), r3);
            r0 = fmaf(ap[4*qq+3], fmaxf(s[0][4*qq+3], dv.w), r0);
            r1 = fmaf(ap[4*qq+3], fmaxf(s[1][4*qq+3], dv.w), r1);
            r2 = fmaf(ap[4*qq+3], fmaxf(s[2][4*qq+3], dv.w), r2);
            r3 = fmaf(ap[4*qq+3], fmaxf(s[3][4*qq+3], dv.w), r3);
        }
        // combine u-halves (partner lane L^16 has the other 16 u's)
        r0 += __shfl_xor(r0, 16);
        r1 += __shfl_xor(r1, 16);
        r2 += __shfl_xor(r2, 16);
        r3 += __shfl_xor(r3, 16);
        const float Dj = Dr[j];
        const short q0 = f2bf(__expf(Dj + r0));
        const short q1 = f2bf(__expf(Dj + r1));
        const short q2 = f2bf(__expf(Dj + r2));
        const short q3 = f2bf(__expf(Dj + r3));
        l0 += bf2f(q0); l1 += bf2f(q1); l2 += bf2f(q2); l3 += bf2f(q3);
        if (!(L & 16)) {                      // one writer per j
            pbf[(4 * w + 0) * PS + j] = q0;
            pbf[(4 * w + 1) * PS + j] = q1;
            pbf[(4 * w + 2) * PS + j] = q2;
            pbf[(4 * w + 3) * PS + j] = q3;
        }
    }

    // wave-reduce l (each j counted twice -> factor 2 in inv)
#pragma unroll
    for (int d = 1; d < 64; d <<= 1) {
        l0 += __shfl_xor(l0, d);
        l1 += __shfl_xor(l1, d);
        l2 += __shfl_xor(l2, d);
        l3 += __shfl_xor(l3, d);
    }
    if (L == 0) {
        lfin[4 * w + 0] = l0; lfin[4 * w + 1] = l1;
        lfin[4 * w + 2] = l2; lfin[4 * w + 3] = l3;
    }
    __syncthreads();

    // ---- Phase C: MFMA  out = p @ src  (wave w: K in [128w,128w+128)) ----
    f32x4 acc0 = {0.f, 0.f, 0.f, 0.f};
    f32x4 acc1 = {0.f, 0.f, 0.f, 0.f};
    const int m  = L & 15;
    const int kl = L >> 4;
#pragma unroll
    for (int s4 = 0; s4 < 4; ++s4) {
        const int k0 = 128 * w + 32 * s4 + kl * 8;
        const short8 af = *(const short8*)&pbf[m * PS + k0];
        const short8 b0 = *(const short8*)&st[m * PS + k0];
        const short8 b1 = *(const short8*)&st[(m + 16) * PS + k0];
        acc0 = __builtin_amdgcn_mfma_f32_16x16x32_bf16(af, b0, acc0, 0, 0, 0);
        acc1 = __builtin_amdgcn_mfma_f32_16x16x32_bf16(af, b1, acc1, 0, 0, 0);
    }
    __syncthreads();                           // all MFMA reads of st done
    f32x4* scr = (f32x4*)(void*)st;            // st dead: 8 KB K-partials
    scr[(w * 2 + 0) * 64 + L] = acc0;
    scr[(w * 2 + 1) * 64 + L] = acc1;
    __syncthreads();

    if (w < 2) {                               // wave w handles N-tile w
        f32x4 sum = scr[(0 * 2 + w) * 64 + L];
        sum += scr[(1 * 2 + w) * 64 + L];
        sum += scr[(2 * 2 + w) * 64 + L];
        sum += scr[(3 * 2 + w) * 64 + L];
#pragma unroll
        for (int r = 0; r < 4; ++r) {
            const int il = kl * 4 + r;         // C/D: row=(lane>>4)*4+reg
            const float inv = 2.0f * __builtin_amdgcn_rcpf(lfin[il]);
            out[(size_t)(b * N_ + ig0 + il) * (H_ * U_) + h * U_ + w * 16 + m]
                = sum[r] * inv;
        }
    }
}

// ---------------------------------------------------------------------------
extern "C" void kernel_launch(void* const* d_in, const int* in_sizes, int n_in,
                              void* d_out, int out_size, void* d_ws, size_t ws_size,
                              hipStream_t stream) {
    const float* x    = (const float*)d_in[0];
    const float* Wsrc = (const float*)d_in[1];
    const float* Wdst = (const float*)d_in[2];
    const float* a    = (const float*)d_in[3];

    float* ws      = (float*)d_ws;
    float* hsrc    = ws;
    float* hdstN   = hsrc + (size_t)B_ * H_ * N_ * U_;
    float* Drow    = hdstN + (size_t)B_ * H_ * N_ * U_;
    float* ascaled = Drow + (size_t)B_ * H_ * N_;

    proj_kernel<<<(B_ * N_) / 8, 256, 0, stream>>>(x, Wsrc, Wdst, a,
                                                   hsrc, hdstN, Drow, ascaled);
    attn_kernel<<<B_ * H_ * (N_ / 16), 256, 0, stream>>>(hsrc, hdstN, Drow,
                                                         ascaled, (float*)d_out);
}